// Round 5
// baseline (211.666 us; speedup 1.0000x reference)
//
#include <hip/hip_runtime.h>
#include <hip/hip_bf16.h>

typedef __attribute__((ext_vector_type(8))) short bf16x8;
typedef __attribute__((ext_vector_type(4))) float f32x4;

#define HW_ 25600
#define HP_ 162
#define WP_ 162

__device__ __forceinline__ unsigned short f2bf(float f) {
    union { float f; unsigned u; } x; x.f = f;
    unsigned r = x.u + 0x7FFFu + ((x.u >> 16) & 1u);
    return (unsigned short)(r >> 16);
}

typedef const __attribute__((address_space(1))) unsigned int* gas_t;
typedef __attribute__((address_space(3))) unsigned int* las_t;
__device__ __forceinline__ void gl_lds16(const void* g, void* l) {
    __builtin_amdgcn_global_load_lds((gas_t)g, (las_t)l, 16, 0, 0);
}

// ---------------- merged: w_iam prep (blocks 0..1151) + fpad border zero (1152..3727)
// wprep[72 stages][128 m][32 k]: stage = tap*8+kc; storage chunk j holds logical chunk j^((m>>1)&3)
__global__ __launch_bounds__(256) void k_prep(const float* __restrict__ w_iam,
                                              unsigned short* __restrict__ wp,
                                              unsigned short* __restrict__ fpad) {
    int bid = blockIdx.x;
    if (bid < 1152) {
        int idx = bid * 256 + threadIdx.x;          // < 294912
        int stage = idx >> 12;
        int r = idx & 4095;
        int m = r >> 5, cl = r & 31;
        int tap = stage >> 3, kc = stage & 7;
        int jj = (cl >> 3) ^ ((m >> 1) & 3);
        int c = kc * 32 + jj * 8 + (cl & 7);
        int dy = (tap * 11) >> 5, dx = tap - dy * 3;
        float v = (m < 100) ? w_iam[((m * 256 + c) * 3 + dy) * 3 + dx] : 0.f;
        wp[idx] = f2bf(v);
    } else {
        int idx = (bid - 1152) * 256 + threadIdx.x;
        const int perb = 164864;
        if (idx >= 4 * perb) return;
        int b = idx / perb;
        int r = idx - b * perb;
        int hp, wpp, c;
        if (r < 82944) {
            hp = (r < 41472) ? 0 : 161;
            int r2 = r % 41472;
            wpp = r2 >> 8; c = r2 & 255;
        } else {
            r -= 82944;
            wpp = (r < 40960) ? 0 : 161;
            int r2 = r % 40960;
            hp = 1 + (r2 >> 8); c = r2 & 255;
        }
        fpad[((b * HP_ + hp) * WP_ + wpp) * 256 + c] = 0;
    }
}

// ---------------- features NCHW fp32 -> fpad[b][h+1][w+1][c] bf16 (LDS transpose)
__global__ __launch_bounds__(256) void k_convert(const float* __restrict__ feat,
                                                 unsigned short* __restrict__ fpad) {
    int bid = blockIdx.x;
    int b = bid / 640;
    int h = (bid >> 2) % 160;
    int c0 = (bid & 3) * 64;
    __shared__ float tile[64][161];
    int t = threadIdx.x;
    const float4* src4 = (const float4*)(feat + ((long)(b * 256 + c0) * 160 + h) * 160);
    #pragma unroll
    for (int s = 0; s < 10; ++s) {
        int q = t + s * 256;                 // 0..2559 float4s
        int ci = q / 40;
        int w4 = q - ci * 40;
        float4 v = src4[(long)ci * 6400 + w4];
        tile[ci][w4 * 4 + 0] = v.x;
        tile[ci][w4 * 4 + 1] = v.y;
        tile[ci][w4 * 4 + 2] = v.z;
        tile[ci][w4 * 4 + 3] = v.w;
    }
    __syncthreads();
    int co = (t & 7) * 8, wq = t >> 3;
    unsigned short* dst = fpad + ((long)(b * HP_ + h + 1) * WP_ + 1) * 256 + c0 + co;
    #pragma unroll
    for (int wp = 0; wp < 5; ++wp) {
        int w = wq + wp * 32;
        bf16x8 v;
        #pragma unroll
        for (int j = 0; j < 8; ++j) v[j] = (short)f2bf(tile[co + j][w]);
        *(bf16x8*)(dst + (long)w * 256) = v;
    }
}

// ---------------- conv GEMM: C[128 masks(100 used)][128 pixels], K=2304, BK=32
// 2x2 wave split, dbuf LDS 32KB, counted vmcnt(4), chunk-XOR swizzle sigma(row)=(row>>1)&3
__global__ __launch_bounds__(256, 3) void k_conv(const unsigned short* __restrict__ fpad,
                                                 const unsigned short* __restrict__ wprep,
                                                 const float* __restrict__ b_iam,
                                                 float* __restrict__ iam) {
    int bid = blockIdx.x;
    bid = (bid & 7) * 100 + (bid >> 3);          // XCD swizzle (800 % 8 == 0, bijective)
    int b = bid / 200;
    int p0 = (bid % 200) * 128;
    int tid = threadIdx.x;
    int lane = tid & 63, wid = tid >> 6;
    int wr = wid >> 1, wc = wid & 1;

    __shared__ __align__(16) unsigned short As[2][4096];   // [buf][128 m x 32 k]
    __shared__ __align__(16) unsigned short Bs[2][4096];   // [buf][128 p x 32 k]

    // B staging: per stage, 2 gl_lds per thread. instr i covers LDS rows i*64+wid*16..+15.
    // lane l -> row rb+(l>>2), dest chunk l&3; source fetches logical chunk (l&3)^((l>>3)&3).
    const unsigned short* fb = fpad + (long)b * HP_ * WP_ * 256;
    const unsigned short* gBsrc[2];
    {
        int swz = ((lane & 3) ^ ((lane >> 3) & 3)) * 8;
        #pragma unroll
        for (int i = 0; i < 2; ++i) {
            int pr = i * 64 + wid * 16 + (lane >> 2);
            int p = p0 + pr;
            int h = p / 160, w = p - h * 160;
            gBsrc[i] = fb + ((long)h * WP_ + w) * 256 + swz;
        }
    }
    const unsigned short* gA0 = wprep + (wid << 9) + (lane << 3);

    f32x4 acc[4][4];
    #pragma unroll
    for (int i = 0; i < 4; ++i)
        #pragma unroll
        for (int j = 0; j < 4; ++j)
            #pragma unroll
            for (int k = 0; k < 4; ++k) acc[i][j][k] = 0.f;

    // frag-read byte offsets (chunk XOR sigma(row), sigma = (row>>1)&3 -> (lane>>1)&3)
    int chB   = (((lane >> 4) ^ ((lane >> 1) & 3)) << 4);
    int aBase = (wr << 12) + ((lane & 15) << 6) + chB;
    int bBase = (wc << 12) + ((lane & 15) << 6) + chB;

    auto issue = [&](int s, int bi) {
        int tap = s >> 3, kc = s & 7;
        int dy = (tap * 11) >> 5, dx = tap - dy * 3;
        long boff = ((long)dy * WP_ + dx) * 256 + kc * 32;
        const unsigned short* ga = gA0 + ((long)s << 12);
        char* Ad = (char*)As[bi] + (wid << 10);
        char* Bd = (char*)Bs[bi] + (wid << 10);
        gl_lds16(ga, Ad);
        gl_lds16(ga + 2048, Ad + 4096);
        gl_lds16(gBsrc[0] + boff, Bd);
        gl_lds16(gBsrc[1] + boff, Bd + 4096);
    };

    auto compute = [&](int bi) {
        const char* Ab = (const char*)As[bi];
        const char* Bb = (const char*)Bs[bi];
        bf16x8 af[4], bfv[4];
        #pragma unroll
        for (int mf = 0; mf < 4; ++mf)
            af[mf] = *(const bf16x8*)(Ab + aBase + (mf << 10));
        #pragma unroll
        for (int nf = 0; nf < 4; ++nf)
            bfv[nf] = *(const bf16x8*)(Bb + bBase + (nf << 10));
        __builtin_amdgcn_s_setprio(1);
        #pragma unroll
        for (int mf = 0; mf < 4; ++mf)
            #pragma unroll
            for (int nf = 0; nf < 4; ++nf)
                acc[mf][nf] = __builtin_amdgcn_mfma_f32_16x16x32_bf16(
                    af[mf], bfv[nf], acc[mf][nf], 0, 0, 0);
        __builtin_amdgcn_s_setprio(0);
    };

    issue(0, 0);
    for (int s = 0; s < 71; ++s) {
        issue(s + 1, (s + 1) & 1);                       // prefetch: full iter of slack
        asm volatile("s_waitcnt vmcnt(4)" ::: "memory"); // stage s landed; s+1 in flight
        __builtin_amdgcn_sched_barrier(0);
        __builtin_amdgcn_s_barrier();
        __builtin_amdgcn_sched_barrier(0);
        compute(s & 1);
        __builtin_amdgcn_sched_barrier(0);
        __builtin_amdgcn_s_barrier();                    // all waves done with buf[s&1]
        __builtin_amdgcn_sched_barrier(0);
    }
    asm volatile("s_waitcnt vmcnt(0)" ::: "memory");
    __builtin_amdgcn_sched_barrier(0);
    __builtin_amdgcn_s_barrier();
    __builtin_amdgcn_sched_barrier(0);
    compute(1);

    // C write: m = wr*64+mf*16+(l>>4)*4+j ; p = p0+wc*64+nf*16+(l&15)
    float* dst = iam + (long)b * 100 * HW_;
    #pragma unroll
    for (int mf = 0; mf < 4; ++mf)
        #pragma unroll
        for (int nf = 0; nf < 4; ++nf) {
            int p = p0 + wc * 64 + nf * 16 + (lane & 15);
            int m0 = wr * 64 + mf * 16 + ((lane >> 4) << 2);
            #pragma unroll
            for (int j = 0; j < 4; ++j) {
                int m = m0 + j;
                if (m < 100) dst[(long)m * HW_ + p] = acc[mf][nf][j] + b_iam[m];
            }
        }
}

// ---------------- split-K pooling: 400 blocks (slice=256px): partials[b][sl][112][256]
__global__ __launch_bounds__(256, 2) void k_pool(const float* __restrict__ feat,
                                                 const float* __restrict__ iam,
                                                 float* __restrict__ partials,
                                                 float* __restrict__ psum) {
    int bid = blockIdx.x;
    int b = bid / 100;
    int slice = bid - b * 100;
    int p0 = slice * 256;
    int tid = threadIdx.x, lane = tid & 63, wq = tid >> 6;

    __shared__ __align__(16) unsigned short A[128 * 72];
    __shared__ __align__(16) unsigned short Bl[256 * 72];
    __shared__ float sums[128];
    if (tid < 128) sums[tid] = 0.f;
    __syncthreads();

    f32x4 acc[7][4];
    #pragma unroll
    for (int i = 0; i < 7; ++i)
        #pragma unroll
        for (int j = 0; j < 4; ++j)
            #pragma unroll
            for (int k = 0; k < 4; ++k) acc[i][j][k] = 0.f;

    int kgrp = (lane >> 4) << 3;

    for (int ks = 0; ks < 4; ++ks) {
        int k0 = p0 + ks * 64;
        for (int s = 0; s < 4; ++s) {
            int q = tid + s * 256;
            int mi = q >> 3, j0 = (q & 7) * 8;
            bf16x8 o;
            if (mi < 100) {
                const float4* sp4 = (const float4*)(iam + (long)(b * 100 + mi) * HW_ + k0 + j0);
                float4 v0 = sp4[0], v1 = sp4[1];
                float xv[8] = {v0.x, v0.y, v0.z, v0.w, v1.x, v1.y, v1.z, v1.w};
                float ls = 0.f;
                #pragma unroll
                for (int j = 0; j < 8; ++j) {
                    float e = __expf(xv[j]);
                    o[j] = (short)f2bf(e);
                    ls += e;
                }
                atomicAdd(&sums[mi], ls);
            } else {
                #pragma unroll
                for (int j = 0; j < 8; ++j) o[j] = 0;
            }
            *(bf16x8*)(A + mi * 72 + j0) = o;
        }
        for (int s = 0; s < 8; ++s) {
            int q = tid + s * 256;
            int ci = q >> 3, j0 = (q & 7) * 8;
            const float4* sp4 = (const float4*)(feat + (long)(b * 256 + ci) * HW_ + k0 + j0);
            float4 v0 = sp4[0], v1 = sp4[1];
            float xv[8] = {v0.x, v0.y, v0.z, v0.w, v1.x, v1.y, v1.z, v1.w};
            bf16x8 o;
            #pragma unroll
            for (int j = 0; j < 8; ++j) o[j] = (short)f2bf(xv[j]);
            *(bf16x8*)(Bl + ci * 72 + j0) = o;
        }
        __syncthreads();
        #pragma unroll
        for (int kk = 0; kk < 64; kk += 32) {
            bf16x8 af[7], bfv[4];
            #pragma unroll
            for (int mf = 0; mf < 7; ++mf)
                af[mf] = *(const bf16x8*)(A + (mf * 16 + (lane & 15)) * 72 + kk + kgrp);
            #pragma unroll
            for (int nf = 0; nf < 4; ++nf)
                bfv[nf] = *(const bf16x8*)(Bl + (wq * 64 + nf * 16 + (lane & 15)) * 72 + kk + kgrp);
            #pragma unroll
            for (int mf = 0; mf < 7; ++mf)
                #pragma unroll
                for (int nf = 0; nf < 4; ++nf)
                    acc[mf][nf] = __builtin_amdgcn_mfma_f32_16x16x32_bf16(
                        af[mf], bfv[nf], acc[mf][nf], 0, 0, 0);
        }
        __syncthreads();
    }
    if (tid < 100) psum[(long)bid * 112 + tid] = sums[tid];
    float* dst = partials + (long)bid * 112 * 256;
    #pragma unroll
    for (int mf = 0; mf < 7; ++mf)
        #pragma unroll
        for (int nf = 0; nf < 4; ++nf) {
            int m0 = mf * 16 + ((lane >> 4) << 2);
            int c  = wq * 64 + nf * 16 + (lane & 15);
            #pragma unroll
            for (int j = 0; j < 4; ++j)
                dst[(long)(m0 + j) * 256 + c] = acc[mf][nf][j];
        }
}

// ---------------- sum 100 partial slices + divide -> inst_pool
__global__ __launch_bounds__(256) void k_redpool(const float* __restrict__ partials,
                                                 const float* __restrict__ psum,
                                                 float* __restrict__ inst_pool) {
    int bid = blockIdx.x;                       // b*100+m
    int b = bid / 100, m = bid - b * 100;
    int c = threadIdx.x;
    float s = 0.f, d = 0.f;
    for (int sl = 0; sl < 100; ++sl) {
        s += partials[((long)(b * 100 + sl) * 112 + m) * 256 + c];
        d += psum[(long)(b * 100 + sl) * 112 + m];
    }
    inst_pool[(long)bid * 256 + c] = s / d;
}

// ---------------- fc + relu + 4 heads (all fp32)
__global__ __launch_bounds__(256) void k_fc(const float* __restrict__ inst_pool,
                                            const float* __restrict__ w_fc, const float* __restrict__ b_fc,
                                            const float* __restrict__ w_cls, const float* __restrict__ b_cls,
                                            const float* __restrict__ w_ker, const float* __restrict__ b_ker,
                                            const float* __restrict__ w_obj, const float* __restrict__ b_obj,
                                            const float* __restrict__ w_box, const float* __restrict__ b_box,
                                            float* __restrict__ out) {
    int r = blockIdx.x;                         // 0..399
    int t = threadIdx.x;
    __shared__ float row[256];
    __shared__ float inst_s[256];
    row[t] = inst_pool[(long)r * 256 + t];
    __syncthreads();
    {
        float acc = b_fc[t];
        const float4* wv = (const float4*)(w_fc + (long)t * 256);
        for (int c = 0; c < 64; ++c) {
            float4 w4 = wv[c];
            acc += w4.x * row[c * 4] + w4.y * row[c * 4 + 1] + w4.z * row[c * 4 + 2] + w4.w * row[c * 4 + 3];
        }
        acc = fmaxf(acc, 0.f);
        inst_s[t] = acc;
        out[10376800 + (long)r * 256 + t] = acc;   // inst
    }
    __syncthreads();
    {
        float acc = b_ker[t];
        const float4* wv = (const float4*)(w_ker + (long)t * 256);
        for (int c = 0; c < 64; ++c) {
            float4 w4 = wv[c];
            acc += w4.x * inst_s[c * 4] + w4.y * inst_s[c * 4 + 1] + w4.z * inst_s[c * 4 + 2] + w4.w * inst_s[c * 4 + 3];
        }
        out[32400 + (long)r * 256 + t] = acc;      // pred_kernel
    }
    if (t < 81) {
        float acc = b_cls[t];
        const float4* wv = (const float4*)(w_cls + (long)t * 256);
        for (int c = 0; c < 64; ++c) {
            float4 w4 = wv[c];
            acc += w4.x * inst_s[c * 4] + w4.y * inst_s[c * 4 + 1] + w4.z * inst_s[c * 4 + 2] + w4.w * inst_s[c * 4 + 3];
        }
        out[(long)r * 81 + t] = acc;               // pred_logits
    }
    if (t == 0) {
        float acc = b_obj[0];
        for (int c = 0; c < 256; ++c) acc += w_obj[c] * inst_s[c];
        out[134800 + r] = acc;                     // pred_scores
    }
    if (t >= 1 && t < 5) {
        int j = t - 1;
        float acc = b_box[j];
        for (int c = 0; c < 256; ++c) acc += w_box[j * 256 + c] * inst_s[c];
        out[135200 + (long)r * 4 + j] = acc;       // pred_bboxes
    }
}

extern "C" void kernel_launch(void* const* d_in, const int* in_sizes, int n_in,
                              void* d_out, int out_size, void* d_ws, size_t ws_size,
                              hipStream_t stream) {
    const float* feat  = (const float*)d_in[0];
    const float* w_iam = (const float*)d_in[1];
    const float* b_iam = (const float*)d_in[2];
    // d_in[3] softmax_bias: uniform shift inside softmax -> cancels exactly
    const float* w_fc  = (const float*)d_in[4];
    const float* b_fc  = (const float*)d_in[5];
    const float* w_cls = (const float*)d_in[6];
    const float* b_cls = (const float*)d_in[7];
    const float* w_ker = (const float*)d_in[8];
    const float* b_ker = (const float*)d_in[9];
    const float* w_obj = (const float*)d_in[10];
    const float* b_obj = (const float*)d_in[11];
    const float* w_box = (const float*)d_in[12];
    const float* b_box = (const float*)d_in[13];
    float* out = (float*)d_out;

    char* ws = (char*)d_ws;
    unsigned short* fpad  = (unsigned short*)ws;               // 53,747,712 B
    unsigned short* wprep = (unsigned short*)(ws + 53747712);  //    589,824 B -> end 54,337,536
    // post-conv phase aliases fpad (dead after k_conv):
    float* partials  = (float*)ws;                             // 45,875,200 B
    float* psum      = (float*)(ws + 45875200);                //    179,200 B
    float* inst_pool = (float*)(ws + 46054400);                //    409,600 B -> 46,464,000

    float* iam = out + 136800;

    k_prep   <<<dim3(3728), dim3(256), 0, stream>>>(w_iam, wprep, fpad);
    k_convert<<<dim3(2560), dim3(256), 0, stream>>>(feat, fpad);
    k_conv   <<<dim3(800),  dim3(256), 0, stream>>>(fpad, wprep, b_iam, iam);
    k_pool   <<<dim3(400),  dim3(256), 0, stream>>>(feat, iam, partials, psum);
    k_redpool<<<dim3(400),  dim3(256), 0, stream>>>(partials, psum, inst_pool);
    k_fc     <<<dim3(400),  dim3(256), 0, stream>>>(inst_pool, w_fc, b_fc, w_cls, b_cls,
                                                    w_ker, b_ker, w_obj, b_obj, w_box, b_box, out);
}

// Round 6
// 191.642 us; speedup vs baseline: 1.1045x; 1.1045x over previous
//
#include <hip/hip_runtime.h>
#include <hip/hip_bf16.h>

typedef __attribute__((ext_vector_type(8))) short bf16x8;
typedef __attribute__((ext_vector_type(4))) float f32x4;

#define HW_ 25600
#define HP_ 162
#define WP_ 162

__device__ __forceinline__ unsigned short f2bf(float f) {
    union { float f; unsigned u; } x; x.f = f;
    unsigned r = x.u + 0x7FFFu + ((x.u >> 16) & 1u);
    return (unsigned short)(r >> 16);
}

typedef const __attribute__((address_space(1))) unsigned int* gas_t;
typedef __attribute__((address_space(3))) unsigned int* las_t;
__device__ __forceinline__ void gl_lds16(const void* g, void* l) {
    __builtin_amdgcn_global_load_lds((gas_t)g, (las_t)l, 16, 0, 0);
}

// ---------------- merged: w_iam prep (blocks 0..1151) + fpad border zero (1152..3727)
// wprep[72 stages][128 m][32 k]: stage = tap*8+kc; storage chunk j holds logical chunk j^((m>>1)&3)
__global__ __launch_bounds__(256) void k_prep(const float* __restrict__ w_iam,
                                              unsigned short* __restrict__ wp,
                                              unsigned short* __restrict__ fpad) {
    int bid = blockIdx.x;
    if (bid < 1152) {
        int idx = bid * 256 + threadIdx.x;          // < 294912
        int stage = idx >> 12;
        int r = idx & 4095;
        int m = r >> 5, cl = r & 31;
        int tap = stage >> 3, kc = stage & 7;
        int jj = (cl >> 3) ^ ((m >> 1) & 3);
        int c = kc * 32 + jj * 8 + (cl & 7);
        int dy = (tap * 11) >> 5, dx = tap - dy * 3;
        float v = (m < 100) ? w_iam[((m * 256 + c) * 3 + dy) * 3 + dx] : 0.f;
        wp[idx] = f2bf(v);
    } else {
        int idx = (bid - 1152) * 256 + threadIdx.x;
        const int perb = 164864;
        if (idx >= 4 * perb) return;
        int b = idx / perb;
        int r = idx - b * perb;
        int hp, wpp, c;
        if (r < 82944) {
            hp = (r < 41472) ? 0 : 161;
            int r2 = r % 41472;
            wpp = r2 >> 8; c = r2 & 255;
        } else {
            r -= 82944;
            wpp = (r < 40960) ? 0 : 161;
            int r2 = r % 40960;
            hp = 1 + (r2 >> 8); c = r2 & 255;
        }
        fpad[((b * HP_ + hp) * WP_ + wpp) * 256 + c] = 0;
    }
}

// ---------------- features NCHW fp32 -> fpad[b][h+1][w+1][c] bf16 (LDS transpose)
__global__ __launch_bounds__(256) void k_convert(const float* __restrict__ feat,
                                                 unsigned short* __restrict__ fpad) {
    int bid = blockIdx.x;
    int b = bid / 640;
    int h = (bid >> 2) % 160;
    int c0 = (bid & 3) * 64;
    __shared__ float tile[64][161];
    int t = threadIdx.x;
    const float4* src4 = (const float4*)(feat + ((long)(b * 256 + c0) * 160 + h) * 160);
    #pragma unroll
    for (int s = 0; s < 10; ++s) {
        int q = t + s * 256;                 // 0..2559 float4s
        int ci = q / 40;
        int w4 = q - ci * 40;
        float4 v = src4[(long)ci * 6400 + w4];
        tile[ci][w4 * 4 + 0] = v.x;
        tile[ci][w4 * 4 + 1] = v.y;
        tile[ci][w4 * 4 + 2] = v.z;
        tile[ci][w4 * 4 + 3] = v.w;
    }
    __syncthreads();
    int co = (t & 7) * 8, wq = t >> 3;
    unsigned short* dst = fpad + ((long)(b * HP_ + h + 1) * WP_ + 1) * 256 + c0 + co;
    #pragma unroll
    for (int wp = 0; wp < 5; ++wp) {
        int w = wq + wp * 32;
        bf16x8 v;
        #pragma unroll
        for (int j = 0; j < 8; ++j) v[j] = (short)f2bf(tile[co + j][w]);
        *(bf16x8*)(dst + (long)w * 256) = v;
    }
}

// ---------------- conv GEMM with dx-sharing: C[128m(100)][128px], K=2304
// 24 stages = 3 dy x 8 kc; each stage: B = 132 contiguous fpad rows x 32ch (one tile
// serves dx=0,1,2 via row offsets), A = 3 dx weight tiles. dbuf, vmcnt(9) counted.
__global__ __launch_bounds__(256, 2) void k_conv(const unsigned short* __restrict__ fpad,
                                                 const unsigned short* __restrict__ wprep,
                                                 const float* __restrict__ b_iam,
                                                 float* __restrict__ iam) {
    int bid = blockIdx.x;
    bid = (bid & 7) * 100 + (bid >> 3);          // XCD swizzle (bijective, 800%8==0)
    int b = bid / 200;
    int p0 = (bid % 200) * 128;
    int tid = threadIdx.x;
    int lane = tid & 63, wid = tid >> 6;
    int wr = wid >> 1, wc = wid & 1;

    // per buffer: A 3*8192 B at 0, B 8448 B at 24576; total 2*33024 = 66048 B
    __shared__ __align__(16) char smem[2][33024];

    int h0 = p0 / 160, w0 = p0 - h0 * 160;
    int istar = 160 - w0;                        // pixel i >= istar wrapped to next raw row (+2)
    const unsigned short* fb = fpad + (long)b * HP_ * WP_ * 256;

    // B staging element-offsets (relative to tile base lin*256 + kc*32):
    // issues 0,1: slot=i*256+tid -> row=i*64+(tid>>2), chunk=tid&3 (src chunk XOR (row>>1)&3)
    long rterm[2];
    {
        int c = tid & 3;
        #pragma unroll
        for (int i = 0; i < 2; ++i) {
            int r = i * 64 + (tid >> 2);
            rterm[i] = (long)r * 256 + ((c ^ ((r >> 1) & 3)) << 3);
        }
    }
    long rterm2;
    {
        int r = 128 + ((lane & 15) >> 2), c = lane & 3;
        rterm2 = (long)r * 256 + ((c ^ ((r >> 1) & 3)) << 3);
    }

    f32x4 acc[4][4];
    #pragma unroll
    for (int i = 0; i < 4; ++i)
        #pragma unroll
        for (int j = 0; j < 4; ++j)
            #pragma unroll
            for (int k = 0; k < 4; ++k) acc[i][j][k] = 0.f;

    // A frag base (within one dx tile): row m = wr*64+mf*16+(lane&15), chunk (lane>>4)^sigma(m)
    int aBase = (wr << 12) + ((lane & 15) << 6) + ((((lane >> 4) ^ ((lane >> 1) & 3))) << 4);
    // B frag row bases per nf (before +dx)
    int rb[4];
    #pragma unroll
    for (int nf = 0; nf < 4; ++nf) {
        int i = wc * 64 + nf * 16 + (lane & 15);
        rb[nf] = i + 2 * (i >= istar);
    }

    auto issue = [&](int s, int bi) {
        int dy = s >> 3, kc = s & 7;
        char* Ad = smem[bi];
        char* Bd = smem[bi] + 24576;
        // A: 3 dx tiles, 2 issues each
        #pragma unroll
        for (int dx = 0; dx < 3; ++dx) {
            const unsigned short* ga = wprep + ((long)((dy * 3 + dx) * 8 + kc) << 12) + (tid << 3);
            char* Adst = Ad + (dx << 13) + (wid << 10);
            gl_lds16(ga, Adst);
            gl_lds16(ga + 2048, Adst + 4096);
        }
        // B: 132 rows x 32ch from contiguous fpad span starting at (h0+dy, w0)
        long base = ((long)((h0 + dy) * WP_ + w0)) * 256 + (kc << 5);
        gl_lds16(fb + base + rterm[0], Bd + (wid << 10));
        gl_lds16(fb + base + rterm[1], Bd + 4096 + (wid << 10));
        if (lane < 16) gl_lds16(fb + base + rterm2, Bd + 8192);
    };

    auto compute = [&](int bi) {
        const char* Ab = smem[bi];
        const char* Bb = smem[bi] + 24576;
        #pragma unroll
        for (int dx = 0; dx < 3; ++dx) {
            bf16x8 af[4], bfv[4];
            #pragma unroll
            for (int mf = 0; mf < 4; ++mf)
                af[mf] = *(const bf16x8*)(Ab + (dx << 13) + aBase + (mf << 10));
            #pragma unroll
            for (int nf = 0; nf < 4; ++nf) {
                int row = rb[nf] + dx;
                bfv[nf] = *(const bf16x8*)(Bb + (row << 6) +
                            ((((lane >> 4) ^ ((row >> 1) & 3))) << 4));
            }
            __builtin_amdgcn_s_setprio(1);
            #pragma unroll
            for (int mf = 0; mf < 4; ++mf)
                #pragma unroll
                for (int nf = 0; nf < 4; ++nf)
                    acc[mf][nf] = __builtin_amdgcn_mfma_f32_16x16x32_bf16(
                        af[mf], bfv[nf], acc[mf][nf], 0, 0, 0);
            __builtin_amdgcn_s_setprio(0);
        }
    };

    issue(0, 0);
    for (int s = 0; s < 23; ++s) {
        issue(s + 1, (s + 1) & 1);
        asm volatile("s_waitcnt vmcnt(9)" ::: "memory");   // own stage-s loads landed
        __builtin_amdgcn_sched_barrier(0);
        __builtin_amdgcn_s_barrier();                      // => ALL waves' stage-s loads landed
        __builtin_amdgcn_sched_barrier(0);
        compute(s & 1);
        __builtin_amdgcn_sched_barrier(0);
        __builtin_amdgcn_s_barrier();                      // all waves done reading buf[s&1]
        __builtin_amdgcn_sched_barrier(0);
    }
    asm volatile("s_waitcnt vmcnt(0)" ::: "memory");
    __builtin_amdgcn_sched_barrier(0);
    __builtin_amdgcn_s_barrier();
    __builtin_amdgcn_sched_barrier(0);
    compute(1);

    // C write: m = wr*64+mf*16+(l>>4)*4+j ; p = p0+wc*64+nf*16+(l&15)
    float* dst = iam + (long)b * 100 * HW_;
    #pragma unroll
    for (int mf = 0; mf < 4; ++mf)
        #pragma unroll
        for (int nf = 0; nf < 4; ++nf) {
            int p = p0 + wc * 64 + nf * 16 + (lane & 15);
            int m0 = wr * 64 + mf * 16 + ((lane >> 4) << 2);
            #pragma unroll
            for (int j = 0; j < 4; ++j) {
                int m = m0 + j;
                if (m < 100) dst[(long)m * HW_ + p] = acc[mf][nf][j] + b_iam[m];
            }
        }
}

// ---------------- split-K pooling (512-px slices, 200 blocks): partials[b][sl][112][256]
__global__ __launch_bounds__(256, 2) void k_pool(const float* __restrict__ feat,
                                                 const float* __restrict__ iam,
                                                 float* __restrict__ partials,
                                                 float* __restrict__ psum) {
    int bid = blockIdx.x;
    int b = bid / 50;
    int slice = bid - b * 50;
    int p0 = slice * 512;
    int tid = threadIdx.x, lane = tid & 63, wq = tid >> 6;

    __shared__ __align__(16) unsigned short A[128 * 72];
    __shared__ __align__(16) unsigned short Bl[256 * 72];
    __shared__ float sums[128];
    if (tid < 128) sums[tid] = 0.f;
    __syncthreads();

    f32x4 acc[7][4];
    #pragma unroll
    for (int i = 0; i < 7; ++i)
        #pragma unroll
        for (int j = 0; j < 4; ++j)
            #pragma unroll
            for (int k = 0; k < 4; ++k) acc[i][j][k] = 0.f;

    int kgrp = (lane >> 4) << 3;

    for (int ks = 0; ks < 8; ++ks) {
        int k0 = p0 + ks * 64;
        for (int s = 0; s < 4; ++s) {
            int q = tid + s * 256;
            int mi = q >> 3, j0 = (q & 7) * 8;
            bf16x8 o;
            if (mi < 100) {
                const float4* sp4 = (const float4*)(iam + (long)(b * 100 + mi) * HW_ + k0 + j0);
                float4 v0 = sp4[0], v1 = sp4[1];
                float xv[8] = {v0.x, v0.y, v0.z, v0.w, v1.x, v1.y, v1.z, v1.w};
                float ls = 0.f;
                #pragma unroll
                for (int j = 0; j < 8; ++j) {
                    float e = __expf(xv[j]);
                    o[j] = (short)f2bf(e);
                    ls += e;
                }
                atomicAdd(&sums[mi], ls);
            } else {
                #pragma unroll
                for (int j = 0; j < 8; ++j) o[j] = 0;
            }
            *(bf16x8*)(A + mi * 72 + j0) = o;
        }
        for (int s = 0; s < 8; ++s) {
            int q = tid + s * 256;
            int ci = q >> 3, j0 = (q & 7) * 8;
            const float4* sp4 = (const float4*)(feat + (long)(b * 256 + ci) * HW_ + k0 + j0);
            float4 v0 = sp4[0], v1 = sp4[1];
            float xv[8] = {v0.x, v0.y, v0.z, v0.w, v1.x, v1.y, v1.z, v1.w};
            bf16x8 o;
            #pragma unroll
            for (int j = 0; j < 8; ++j) o[j] = (short)f2bf(xv[j]);
            *(bf16x8*)(Bl + ci * 72 + j0) = o;
        }
        __syncthreads();
        #pragma unroll
        for (int kk = 0; kk < 64; kk += 32) {
            bf16x8 af[7], bfv[4];
            #pragma unroll
            for (int mf = 0; mf < 7; ++mf)
                af[mf] = *(const bf16x8*)(A + (mf * 16 + (lane & 15)) * 72 + kk + kgrp);
            #pragma unroll
            for (int nf = 0; nf < 4; ++nf)
                bfv[nf] = *(const bf16x8*)(Bl + (wq * 64 + nf * 16 + (lane & 15)) * 72 + kk + kgrp);
            #pragma unroll
            for (int mf = 0; mf < 7; ++mf)
                #pragma unroll
                for (int nf = 0; nf < 4; ++nf)
                    acc[mf][nf] = __builtin_amdgcn_mfma_f32_16x16x32_bf16(
                        af[mf], bfv[nf], acc[mf][nf], 0, 0, 0);
        }
        __syncthreads();
    }
    if (tid < 100) psum[(long)bid * 112 + tid] = sums[tid];
    float* dst = partials + (long)bid * 112 * 256;
    #pragma unroll
    for (int mf = 0; mf < 7; ++mf)
        #pragma unroll
        for (int nf = 0; nf < 4; ++nf) {
            int m0 = mf * 16 + ((lane >> 4) << 2);
            int c  = wq * 64 + nf * 16 + (lane & 15);
            #pragma unroll
            for (int j = 0; j < 4; ++j)
                dst[(long)(m0 + j) * 256 + c] = acc[mf][nf][j];
        }
}

// ---------------- sum 50 partial slices + divide -> inst_pool
__global__ __launch_bounds__(256) void k_redpool(const float* __restrict__ partials,
                                                 const float* __restrict__ psum,
                                                 float* __restrict__ inst_pool) {
    int bid = blockIdx.x;                       // b*100+m
    int b = bid / 100, m = bid - b * 100;
    int c = threadIdx.x;
    float s = 0.f, d = 0.f;
    for (int sl = 0; sl < 50; ++sl) {
        s += partials[((long)(b * 50 + sl) * 112 + m) * 256 + c];
        d += psum[(long)(b * 50 + sl) * 112 + m];
    }
    inst_pool[(long)bid * 256 + c] = s / d;
}

// ---------------- fc + relu + 4 heads (all fp32)
__global__ __launch_bounds__(256) void k_fc(const float* __restrict__ inst_pool,
                                            const float* __restrict__ w_fc, const float* __restrict__ b_fc,
                                            const float* __restrict__ w_cls, const float* __restrict__ b_cls,
                                            const float* __restrict__ w_ker, const float* __restrict__ b_ker,
                                            const float* __restrict__ w_obj, const float* __restrict__ b_obj,
                                            const float* __restrict__ w_box, const float* __restrict__ b_box,
                                            float* __restrict__ out) {
    int r = blockIdx.x;                         // 0..399
    int t = threadIdx.x;
    __shared__ float row[256];
    __shared__ float inst_s[256];
    row[t] = inst_pool[(long)r * 256 + t];
    __syncthreads();
    {
        float acc = b_fc[t];
        const float4* wv = (const float4*)(w_fc + (long)t * 256);
        for (int c = 0; c < 64; ++c) {
            float4 w4 = wv[c];
            acc += w4.x * row[c * 4] + w4.y * row[c * 4 + 1] + w4.z * row[c * 4 + 2] + w4.w * row[c * 4 + 3];
        }
        acc = fmaxf(acc, 0.f);
        inst_s[t] = acc;
        out[10376800 + (long)r * 256 + t] = acc;   // inst
    }
    __syncthreads();
    {
        float acc = b_ker[t];
        const float4* wv = (const float4*)(w_ker + (long)t * 256);
        for (int c = 0; c < 64; ++c) {
            float4 w4 = wv[c];
            acc += w4.x * inst_s[c * 4] + w4.y * inst_s[c * 4 + 1] + w4.z * inst_s[c * 4 + 2] + w4.w * inst_s[c * 4 + 3];
        }
        out[32400 + (long)r * 256 + t] = acc;      // pred_kernel
    }
    if (t < 81) {
        float acc = b_cls[t];
        const float4* wv = (const float4*)(w_cls + (long)t * 256);
        for (int c = 0; c < 64; ++c) {
            float4 w4 = wv[c];
            acc += w4.x * inst_s[c * 4] + w4.y * inst_s[c * 4 + 1] + w4.z * inst_s[c * 4 + 2] + w4.w * inst_s[c * 4 + 3];
        }
        out[(long)r * 81 + t] = acc;               // pred_logits
    }
    if (t == 0) {
        float acc = b_obj[0];
        for (int c = 0; c < 256; ++c) acc += w_obj[c] * inst_s[c];
        out[134800 + r] = acc;                     // pred_scores
    }
    if (t >= 1 && t < 5) {
        int j = t - 1;
        float acc = b_box[j];
        for (int c = 0; c < 256; ++c) acc += w_box[j * 256 + c] * inst_s[c];
        out[135200 + (long)r * 4 + j] = acc;       // pred_bboxes
    }
}

extern "C" void kernel_launch(void* const* d_in, const int* in_sizes, int n_in,
                              void* d_out, int out_size, void* d_ws, size_t ws_size,
                              hipStream_t stream) {
    const float* feat  = (const float*)d_in[0];
    const float* w_iam = (const float*)d_in[1];
    const float* b_iam = (const float*)d_in[2];
    // d_in[3] softmax_bias: uniform shift inside softmax -> cancels exactly
    const float* w_fc  = (const float*)d_in[4];
    const float* b_fc  = (const float*)d_in[5];
    const float* w_cls = (const float*)d_in[6];
    const float* b_cls = (const float*)d_in[7];
    const float* w_ker = (const float*)d_in[8];
    const float* b_ker = (const float*)d_in[9];
    const float* w_obj = (const float*)d_in[10];
    const float* b_obj = (const float*)d_in[11];
    const float* w_box = (const float*)d_in[12];
    const float* b_box = (const float*)d_in[13];
    float* out = (float*)d_out;

    char* ws = (char*)d_ws;
    unsigned short* fpad  = (unsigned short*)ws;               // 53,747,712 B
    unsigned short* wprep = (unsigned short*)(ws + 53747712);  //    589,824 B -> end 54,337,536
    // post-conv phase aliases fpad (dead after k_conv):
    float* partials  = (float*)ws;                             // 22,937,600 B
    float* psum      = (float*)(ws + 22937600);                //     89,600 B
    float* inst_pool = (float*)(ws + 23027200);                //    409,600 B

    float* iam = out + 136800;

    k_prep   <<<dim3(3728), dim3(256), 0, stream>>>(w_iam, wprep, fpad);
    k_convert<<<dim3(2560), dim3(256), 0, stream>>>(feat, fpad);
    k_conv   <<<dim3(800),  dim3(256), 0, stream>>>(fpad, wprep, b_iam, iam);
    k_pool   <<<dim3(200),  dim3(256), 0, stream>>>(feat, iam, partials, psum);
    k_redpool<<<dim3(400),  dim3(256), 0, stream>>>(partials, psum, inst_pool);
    k_fc     <<<dim3(400),  dim3(256), 0, stream>>>(inst_pool, w_fc, b_fc, w_cls, b_cls,
                                                    w_ker, b_ker, w_obj, b_obj, w_box, b_box, out);
}